// Round 5
// baseline (124.378 us; speedup 1.0000x reference)
//
#include <hip/hip_runtime.h>
#include <hip/hip_bf16.h>

typedef unsigned int u32;
typedef unsigned short u16;
typedef float f32x2 __attribute__((ext_vector_type(2)));
typedef float f32x4 __attribute__((ext_vector_type(4)));
using bf16x8 = __attribute__((ext_vector_type(8))) short;   // MFMA A/B frag (4 VGPRs)
using f32x4v = __attribute__((ext_vector_type(4))) float;   // MFMA C/D frag

#define DEVINL __device__ __forceinline__

// Problem constants: B=8, C=64, D=128, H=128, W=128
constexpr int XTS = 136;                     // u16 stride for [pos][d] LDS rows (272 B = 17*16)
constexpr int XT_BYTES = 128 * XTS * 2;      // 34816 — the ONLY main-kernel LDS buffer
constexpr int XS = 132;                      // stride for k_final
constexpr int LDS_X = 128 * XS * 2;          // 33792

DEVINL float bf2f(u16 u) { union { u32 i; float f; } v; v.i = ((u32)u) << 16; return v.f; }
DEVINL float bf2f_lo(u32 u) { union { u32 i; float f; } v; v.i = u << 16; return v.f; }
DEVINL float bf2f_hi(u32 u) { union { u32 i; float f; } v; v.i = u & 0xffff0000u; return v.f; }
DEVINL u16 f2bf(float f) {
  union { float f; u32 i; } v; v.f = f;
  u32 b = v.i;
  b += 0x7fffu + ((b >> 16) & 1u);   // RNE
  return (u16)(b >> 16);
}
DEVINL u32 pack2(float a, float b) { return (u32)f2bf(a) | ((u32)f2bf(b) << 16); }

// ---------------- P0: A=tanh(A_param), Mrow[dir][c][d] bf16, beff ----------------
__global__ __launch_bounds__(256) void k_pre(
    const float* __restrict__ Wf, const float* __restrict__ Wo,
    const float* __restrict__ bf_, const float* __restrict__ bo,
    const float* __restrict__ A_param,
    float* __restrict__ A_t, float* __restrict__ beff, u16* __restrict__ Mrow) {
  const int wg = blockIdx.x, t = threadIdx.x;
  if (wg < 128) {
    const int idx = wg * 256 + t;          // 0..32767
    const int cout = idx >> 9;             // 0..63
    const int k = idx & 511;               // 0..511 = dir*128 + d
    float s = 0.f;
    for (int d = 0; d < 128; ++d) s = fmaf(Wo[cout * 128 + d], Wf[d * 512 + k], s);
    const int dir = k >> 7, dm = k & 127;
    Mrow[(dir * 64 + cout) * 128 + dm] = f2bf(s);
  } else {
    if (t < 128) A_t[t] = tanhf(A_param[t]);
    if (t < 64) {
      float s = bo[t];
      for (int d = 0; d < 128; ++d) s = fmaf(Wo[t * 128 + d], bf_[d], s);
      beff[t] = s;
    }
  }
}

extern __shared__ char smem[];

// In-place scan of a d-pair column (u32 = 2 bf16), 8-deep rolling prefetch.
template <bool REV>
DEVINL void scan_pair(u16* buf, int dp, float A0, float A1, float B0, float B1) {
  float h0 = 0.f, h1 = 0.f;
  u32* base = (u32*)(buf + dp * 2);
  constexpr int RS = XTS / 2;   // 68 dwords per row
  u32 nx[8];
#pragma unroll
  for (int j = 0; j < 8; ++j) nx[j] = base[(REV ? (127 - j) : j) * RS];
  for (int ib = 0; ib < 128; ib += 8) {
    u32 cur[8];
#pragma unroll
    for (int j = 0; j < 8; ++j) cur[j] = nx[j];
    if (ib + 8 < 128) {
#pragma unroll
      for (int j = 0; j < 8; ++j) {
        const int i = ib + 8 + j;
        nx[j] = base[(REV ? (127 - i) : i) * RS];
      }
    }
#pragma unroll
    for (int j = 0; j < 8; ++j) {
      const int i = ib + j;
      h0 = fmaf(A0, h0, B0 * bf2f_lo(cur[j]));
      h1 = fmaf(A1, h1, B1 * bf2f_hi(cur[j]));
      base[(REV ? (127 - i) : i) * RS] = pack2(h0, h1);
    }
  }
}

// One direction of the combine: acc2 += M[dir] @ h  (h in buf as [pos][d] bf16).
DEVINL void combine_pass(const u16* Hbuf, const u16* __restrict__ Mrow, int dir,
                         int lane, int wv, f32x4v (&acc2)[4][2]) {
  const int l15 = lane & 15, kg = lane >> 4;
#pragma unroll
  for (int ks = 0; ks < 4; ++ks) {
    bf16x8 afr[4], bfr[2];
#pragma unroll
    for (int ct = 0; ct < 4; ++ct)
      afr[ct] = *(const bf16x8*)(Mrow + ((size_t)dir * 64 + ct * 16 + l15) * 128 + ks * 32 + kg * 8);
#pragma unroll
    for (int pt = 0; pt < 2; ++pt)
      bfr[pt] = *(const bf16x8*)((const char*)Hbuf + (wv * 32 + pt * 16 + l15) * (XTS * 2) + ks * 64 + kg * 16);
#pragma unroll
    for (int ct = 0; ct < 4; ++ct)
#pragma unroll
      for (int pt = 0; pt < 2; ++pt)
        acc2[ct][pt] = __builtin_amdgcn_mfma_f32_16x16x32_bf16(afr[ct], bfr[pt], acc2[ct][pt], 0, 0, 0);
  }
}

// Store combine acc to OutS (f32 [64][134]) staged in buf.
DEVINL void acc_to_outs(const f32x4v (&acc2)[4][2], int lane, int wv, float* OutS) {
  const int l15 = lane & 15, kg = lane >> 4;
#pragma unroll
  for (int ct = 0; ct < 4; ++ct)
#pragma unroll
    for (int pt = 0; pt < 2; ++pt)
#pragma unroll
      for (int r = 0; r < 4; ++r)
        OutS[(ct * 16 + kg * 4 + r) * 134 + wv * 32 + pt * 16 + l15] = acc2[ct][pt][r];
}

// ---------------- P1: x = Wi@F_mod + bi (MFMA, direct global A), scans, combine ----------------
__global__ __launch_bounds__(256, 4) void k_horiz(
    const float* __restrict__ F_in, const float* __restrict__ prior,
    const float* __restrict__ Wi, const float* __restrict__ bi,
    const float* __restrict__ Bp, const float* __restrict__ alpha_p,
    const float* __restrict__ A_t, const u16* __restrict__ Mrow,
    u16* __restrict__ x_out, u16* __restrict__ Sh) {
  u16* buf = (u16*)smem;        // [128 pos][XTS] bf16 — x / h_lr / h_rl
  float* OutS = (float*)smem;   // epilogue union

  const int t = threadIdx.x;
  const int lane = t & 63, wv = t >> 6, l15 = lane & 15, kg = lane >> 4;
  const int bid = blockIdx.x, b = bid >> 7, h = bid & 127;

  // ---- Wi B-frags (k=c, n=d) into regs ----
  bf16x8 bWi[8][2];
#pragma unroll
  for (int nt = 0; nt < 8; ++nt)
#pragma unroll
    for (int ks = 0; ks < 2; ++ks) {
      const float* wp = Wi + (nt * 16 + l15) * 64 + ks * 32 + kg * 8;
      const f32x4 a = *(const f32x4*)(wp);
      const f32x4 c = *(const f32x4*)(wp + 4);
      union { bf16x8 v; uint4 u; } cv;
      cv.u.x = pack2(a.x, a.y);  cv.u.y = pack2(a.z, a.w);
      cv.u.z = pack2(c.x, c.y);  cv.u.w = pack2(c.z, c.w);
      bWi[nt][ks] = cv.v;
    }

  // ---- x-MFMA: A-frags straight from global (Fmod rows), acc init = bias ----
  {
    const float alpha = alpha_p[0];
    float pv[2];
#pragma unroll
    for (int mt = 0; mt < 2; ++mt)
      pv[mt] = prior[(b * 128 + h) * 128 + wv * 32 + mt * 16 + l15];

    f32x4v acc[2][8];
#pragma unroll
    for (int mt = 0; mt < 2; ++mt)
#pragma unroll
      for (int nt = 0; nt < 8; ++nt) {
        const float bv = bi[nt * 16 + l15];
        acc[mt][nt] = (f32x4v){ bv, bv, bv, bv };
      }

#pragma unroll
    for (int ks = 0; ks < 2; ++ks) {
      bf16x8 aF[2];
#pragma unroll
      for (int mt = 0; mt < 2; ++mt) {
        const int w = wv * 32 + mt * 16 + l15;
        const float* Fp = F_in + (size_t)b * 1048576 + (size_t)(ks * 32 + kg * 8) * 16384 + h * 128 + w;
        float fv[8];
#pragma unroll
        for (int j = 0; j < 8; ++j) fv[j] = fmaf(alpha, pv[mt], Fp[(size_t)j * 16384]);
        union { bf16x8 v; uint4 u; } cv;
        cv.u.x = pack2(fv[0], fv[1]); cv.u.y = pack2(fv[2], fv[3]);
        cv.u.z = pack2(fv[4], fv[5]); cv.u.w = pack2(fv[6], fv[7]);
        aF[mt] = cv.v;
      }
#pragma unroll
      for (int mt = 0; mt < 2; ++mt)
#pragma unroll
        for (int nt = 0; nt < 8; ++nt)
          acc[mt][nt] = __builtin_amdgcn_mfma_f32_16x16x32_bf16(aF[mt], bWi[nt][ks], acc[mt][nt], 0, 0, 0);
    }

    // write x -> buf [w][d] bf16
#pragma unroll
    for (int mt = 0; mt < 2; ++mt)
#pragma unroll
      for (int nt = 0; nt < 8; ++nt)
#pragma unroll
        for (int r = 0; r < 4; ++r)
          buf[(wv * 32 + mt * 16 + kg * 4 + r) * XTS + nt * 16 + l15] = f2bf(acc[mt][nt][r]);
  }
  __syncthreads();

  // ---- read x rows into regs (kept for rev scan), write x_out global ----
  uint4 rld[8];
  {
    u16* xg = x_out + (size_t)(b * 128 + h) * 16384;   // [w][d] plane
#pragma unroll
    for (int j = 0; j < 8; ++j) {
      const int i = t + j * 256;
      rld[j] = *(const uint4*)((const char*)buf + (i >> 4) * (XTS * 2) + (i & 15) * 16);
      *(uint4*)(xg + (i >> 4) * 128 + (i & 15) * 8) = rld[j];
    }
  }
  __syncthreads();

  // ---- fwd scan (lr) in place: 2 waves x 32 lanes, u32 d-pairs ----
  if (t < 128 && lane < 32) {
    const int p = wv * 32 + lane;
    const f32x2 a = *(const f32x2*)(A_t + p * 2);
    const f32x2 bb = *(const f32x2*)(Bp + p * 2);
    scan_pair<false>(buf, p, a.x, a.y, bb.x, bb.y);
  }
  __syncthreads();

  // ---- combine pass 1 (M_lr @ h_lr) ----
  f32x4v acc2[4][2];
#pragma unroll
  for (int i = 0; i < 4; ++i)
#pragma unroll
    for (int j = 0; j < 2; ++j) acc2[i][j] = (f32x4v)0.f;
  combine_pass(buf, Mrow, 0, lane, wv, acc2);
  __syncthreads();

  // ---- restore x from regs ----
#pragma unroll
  for (int j = 0; j < 8; ++j) {
    const int i = t + j * 256;
    *(uint4*)((char*)buf + (i >> 4) * (XTS * 2) + (i & 15) * 16) = rld[j];
  }
  __syncthreads();

  // ---- rev scan (rl) in place ----
  if (t < 128 && lane < 32) {
    const int p = wv * 32 + lane;
    const f32x2 a = *(const f32x2*)(A_t + p * 2);
    const f32x2 bb = *(const f32x2*)(Bp + p * 2);
    scan_pair<true>(buf, p, a.x, a.y, bb.x, bb.y);
  }
  __syncthreads();

  // ---- combine pass 2 (M_rl @ h_rl) ----
  combine_pass(buf, Mrow, 1, lane, wv, acc2);
  __syncthreads();

  acc_to_outs(acc2, lane, wv, OutS);
  __syncthreads();

  // ---- Sh[b][c][h][w] bf16 ----
  u16* sg = Sh + ((size_t)(b * 64) * 128 + h) * 128;
  for (int i = t; i < 4096; i += 256) {
    const int c = i >> 6, w2 = (i & 63) * 2;
    const f32x2 v = *(const f32x2*)(OutS + c * 134 + w2);
    *(u32*)(sg + (size_t)c * 16384 + w2) = pack2(v.x, v.y);
  }
}

// ---------------- P2: vertical scans tb/bt + combine -> accT[b,c,w,h] ----------------
__global__ __launch_bounds__(256, 4) void k_vert(
    const u16* __restrict__ x_ws, const float* __restrict__ Bp,
    const float* __restrict__ A_t, const u16* __restrict__ Mrow,
    u16* __restrict__ accT) {
  u16* buf = (u16*)smem;
  float* OutS = (float*)smem;

  const int t = threadIdx.x;
  const int lane = t & 63, wv = t >> 6;
  const int bid = blockIdx.x, b = bid >> 7, w = bid & 127;

  // ---- load x[b][:][w][:] into regs (kept for rev scan), stage to buf ----
  uint4 rld[8];
#pragma unroll
  for (int j = 0; j < 8; ++j) {
    const int i = t + j * 256;
    rld[j] = *(const uint4*)(x_ws + ((size_t)(b * 128 + (i >> 4)) * 128 + w) * 128 + (i & 15) * 8);
  }
#pragma unroll
  for (int j = 0; j < 8; ++j) {
    const int i = t + j * 256;
    *(uint4*)((char*)buf + (i >> 4) * (XTS * 2) + (i & 15) * 16) = rld[j];
  }
  __syncthreads();

  // ---- fwd scan (tb) ----
  if (t < 128 && lane < 32) {
    const int p = wv * 32 + lane;
    const f32x2 a = *(const f32x2*)(A_t + p * 2);
    const f32x2 bb = *(const f32x2*)(Bp + p * 2);
    scan_pair<false>(buf, p, a.x, a.y, bb.x, bb.y);
  }
  __syncthreads();

  f32x4v acc2[4][2];
#pragma unroll
  for (int i = 0; i < 4; ++i)
#pragma unroll
    for (int j = 0; j < 2; ++j) acc2[i][j] = (f32x4v)0.f;
  combine_pass(buf, Mrow, 2, lane, wv, acc2);
  __syncthreads();

#pragma unroll
  for (int j = 0; j < 8; ++j) {
    const int i = t + j * 256;
    *(uint4*)((char*)buf + (i >> 4) * (XTS * 2) + (i & 15) * 16) = rld[j];
  }
  __syncthreads();

  // ---- rev scan (bt) ----
  if (t < 128 && lane < 32) {
    const int p = wv * 32 + lane;
    const f32x2 a = *(const f32x2*)(A_t + p * 2);
    const f32x2 bb = *(const f32x2*)(Bp + p * 2);
    scan_pair<true>(buf, p, a.x, a.y, bb.x, bb.y);
  }
  __syncthreads();

  combine_pass(buf, Mrow, 3, lane, wv, acc2);
  __syncthreads();

  acc_to_outs(acc2, lane, wv, OutS);
  __syncthreads();

  // ---- accT[b][c][w][h] bf16 ----
  for (int i = t; i < 4096; i += 256) {
    const int c = i >> 6, h2 = (i & 63) * 2;
    const f32x2 v = *(const f32x2*)(OutS + c * 134 + h2);
    *(u32*)(accT + ((size_t)(b * 64 + c) * 128 + w) * 128 + h2) = pack2(v.x, v.y);
  }
}

// ---------------- F: out = F_mod + gamma*(S_h + S_v^T + beff) ----------------
__global__ __launch_bounds__(256) void k_final(
    const float* __restrict__ F_in, const float* __restrict__ prior,
    const float* __restrict__ alpha_p, const float* __restrict__ gamma_p,
    const float* __restrict__ beff, const u16* __restrict__ accT,
    const u16* __restrict__ Sh, float* __restrict__ out) {
  u16* Xu = (u16*)smem;
  u32* Xw = (u32*)smem;
  const int t = threadIdx.x;
  const int bid = blockIdx.x, b = bid >> 6, c = bid & 63;
  const size_t base = (size_t)bid * 16384;   // (b,c) plane

  for (int i = t; i < 2048; i += 256) {
    const int r = i >> 4, j = i & 15;   // r = w row of accT plane
    const uint4 v = *(const uint4*)(accT + base + r * 128 + j * 8);
    u32* dst = Xw + r * 66 + j * 4;
    dst[0] = v.x; dst[1] = v.y; dst[2] = v.z; dst[3] = v.w;
  }
  __syncthreads();
  const float alpha = alpha_p[0], gamma = gamma_p[0];
  const float be = beff[c];
  for (int i = t; i < 2048; i += 256) {
    const int hh = i >> 4, w8 = (i & 15) * 8;
    float sv[8];
#pragma unroll
    for (int q = 0; q < 8; ++q) sv[q] = bf2f(Xu[(w8 + q) * XS + hh]);
    const size_t off = base + hh * 128 + w8;
    const float* Fp = F_in + off;
    const u16* Sp = Sh + off;
    float* Op = out + off;
    const float* Pp = prior + (b * 128 + hh) * 128 + w8;
    const uint4 sh4 = *(const uint4*)(Sp);
    const u16* sh8 = (const u16*)&sh4;
#pragma unroll
    for (int q = 0; q < 8; ++q) {
      Op[q] = Fp[q] + alpha * Pp[q] + gamma * (bf2f(sh8[q]) + be + sv[q]);
    }
  }
}

extern "C" void kernel_launch(void* const* d_in, const int* in_sizes, int n_in,
                              void* d_out, int out_size, void* d_ws, size_t ws_size,
                              hipStream_t stream) {
  const float* F_in   = (const float*)d_in[0];
  const float* prior  = (const float*)d_in[1];
  const float* Wi     = (const float*)d_in[2];
  const float* bi     = (const float*)d_in[3];
  const float* A_par  = (const float*)d_in[4];
  const float* B_par  = (const float*)d_in[5];
  const float* alpha  = (const float*)d_in[6];
  const float* gamma  = (const float*)d_in[7];
  const float* Wf     = (const float*)d_in[8];
  const float* bf_    = (const float*)d_in[9];
  const float* Wo     = (const float*)d_in[10];
  const float* bo     = (const float*)d_in[11];
  float* out = (float*)d_out;

  char* ws = (char*)d_ws;
  float* A_t   = (float*)ws;                       // 512 B
  float* beff  = (float*)(ws + 512);               // 256 B
  u16*   Mrow  = (u16*)(ws + 1024);                // 64 KB: [4][64][128] bf16
  u16*   x_ws  = (u16*)(ws + 66560);               // 33.5 MB: x[b][h][w][d] bf16
  u16*   Sh_ws = (u16*)(ws + 66560 + 33554432);    // 16.8 MB: [b][c][h][w] bf16
  u16*   accT  = (u16*)(ws + 66560 + 50331648);    // 16.8 MB: [b][c][w][h] bf16

  hipFuncSetAttribute((const void*)k_horiz, hipFuncAttributeMaxDynamicSharedMemorySize, XT_BYTES);
  hipFuncSetAttribute((const void*)k_vert,  hipFuncAttributeMaxDynamicSharedMemorySize, XT_BYTES);

  k_pre  <<<129, 256, 0, stream>>>(Wf, Wo, bf_, bo, A_par, A_t, beff, Mrow);
  k_horiz<<<1024, 256, XT_BYTES, stream>>>(F_in, prior, Wi, bi, B_par, alpha, A_t, Mrow, x_ws, Sh_ws);
  k_vert <<<1024, 256, XT_BYTES, stream>>>(x_ws, B_par, A_t, Mrow, accT);
  k_final<<<512, 256, LDS_X, stream>>>(F_in, prior, alpha, gamma, beff, accT, Sh_ws, out);
}